// Round 2
// baseline (521.886 us; speedup 1.0000x reference)
//
#include <hip/hip_runtime.h>

typedef __attribute__((ext_vector_type(8))) __bf16 bf16x8;
typedef __attribute__((ext_vector_type(4))) __bf16 bf16x4;
typedef __attribute__((ext_vector_type(4))) float f32x4;

#define GLD16(gp, lp) __builtin_amdgcn_global_load_lds( \
    (const __attribute__((address_space(1))) void*)(gp), \
    (__attribute__((address_space(3))) void*)(lp), 16, 0, 0)

// ---------------- f32 -> bf16 conversion ----------------
__global__ __launch_bounds__(256) void cvt_f32_bf16(const float* __restrict__ in,
                                                    __bf16* __restrict__ out, long n) {
  long stride = (long)gridDim.x * 256 * 8;
  for (long i = ((long)blockIdx.x * 256 + threadIdx.x) * 8; i < n; i += stride) {
    float4 a = *(const float4*)(in + i);
    float4 b = *(const float4*)(in + i + 4);
    bf16x8 o;
    o[0] = (__bf16)a.x; o[1] = (__bf16)a.y; o[2] = (__bf16)a.z; o[3] = (__bf16)a.w;
    o[4] = (__bf16)b.x; o[5] = (__bf16)b.y; o[6] = (__bf16)b.z; o[7] = (__bf16)b.w;
    *(bf16x8*)(out + i) = o;
  }
}

// ---------------- generic C = A @ B^T (+bias) GEMM ----------------
// A [M][K], BT [N][K] bf16 row-major (both K-major). BM=BN=128, BK=32, 4 waves.
// EPI 0: C bf16 row-major [M][N] + bias
// EPI 1: C bf16 transposed per batch: C[batch][n][tok], batch=row/tokPerBatch (+bias)
// EPI 2: C f32 row-major [M][N], no bias
template <int EPI>
__global__ __launch_bounds__(256) void gemm_bt(
    const __bf16* __restrict__ A, const __bf16* __restrict__ BT,
    void* __restrict__ Cv, const float* __restrict__ bias,
    int M, int N, int K,
    long aBatch, long bBatch, long cBatch, int tokPerBatch) {
  __shared__ __bf16 As[128 * 32];
  __shared__ __bf16 Bs[128 * 32];

  const int t = threadIdx.x;
  const int w = t >> 6, l = t & 63;
  const int wr = w >> 1, wc = w & 1;
  const int lr = l & 15, lg = l >> 4;

  const int m0 = blockIdx.y * 128, n0 = blockIdx.x * 128;
  const int z = blockIdx.z;
  const __bf16* Ab = A + (long)z * aBatch + (long)m0 * K;
  const __bf16* Bb = BT + (long)z * bBatch + (long)n0 * K;

  // staging map: thread t loads row (t>>2), cols (t&3)*8 .. +7
  const int srow = t >> 2, scol = (t & 3) * 8;
  const __bf16* ag0 = Ab + (long)srow * K + scol;
  const __bf16* bg0 = Bb + (long)srow * K + scol;
  char* lA = (char*)As + w * 1024;  // wave-uniform LDS base; HW adds lane*16
  char* lB = (char*)Bs + w * 1024;

  f32x4 acc[4][4];
#pragma unroll
  for (int m = 0; m < 4; ++m)
#pragma unroll
    for (int n = 0; n < 4; ++n) acc[m][n] = (f32x4){0.f, 0.f, 0.f, 0.f};

  for (int k0 = 0; k0 < K; k0 += 32) {
    __syncthreads();
    GLD16(ag0 + k0, lA);
    GLD16(ag0 + (long)64 * K + k0, lA + 4096);
    GLD16(bg0 + k0, lB);
    GLD16(bg0 + (long)64 * K + k0, lB + 4096);
    __syncthreads();

    bf16x8 af[4], bf[4];
#pragma unroll
    for (int m = 0; m < 4; ++m)
      af[m] = *(const bf16x8*)&As[(wr * 64 + m * 16 + lr) * 32 + lg * 8];
#pragma unroll
    for (int n = 0; n < 4; ++n)
      bf[n] = *(const bf16x8*)&Bs[(wc * 64 + n * 16 + lr) * 32 + lg * 8];
#pragma unroll
    for (int m = 0; m < 4; ++m)
#pragma unroll
      for (int n = 0; n < 4; ++n)
        acc[m][n] = __builtin_amdgcn_mfma_f32_16x16x32_bf16(af[m], bf[n], acc[m][n], 0, 0, 0);
  }

  if constexpr (EPI == 0) {
    __bf16* C = (__bf16*)Cv + (long)z * cBatch;
#pragma unroll
    for (int m = 0; m < 4; ++m)
#pragma unroll
      for (int n = 0; n < 4; ++n) {
        int colg = n0 + wc * 64 + n * 16 + lr;
        float bv = bias ? bias[colg] : 0.f;
#pragma unroll
        for (int r = 0; r < 4; ++r) {
          int rowg = m0 + wr * 64 + m * 16 + lg * 4 + r;
          C[(long)rowg * N + colg] = (__bf16)(acc[m][n][r] + bv);
        }
      }
  } else if constexpr (EPI == 2) {
    float* C = (float*)Cv + (long)z * cBatch;
#pragma unroll
    for (int m = 0; m < 4; ++m)
#pragma unroll
      for (int n = 0; n < 4; ++n) {
        int colg = n0 + wc * 64 + n * 16 + lr;
#pragma unroll
        for (int r = 0; r < 4; ++r) {
          int rowg = m0 + wr * 64 + m * 16 + lg * 4 + r;
          C[(long)rowg * N + colg] = acc[m][n][r];
        }
      }
  } else {
    // transposed epilogue via LDS: Cs[col][row], ld = 136
    __shared__ __bf16 Cs[128 * 136];
#pragma unroll
    for (int m = 0; m < 4; ++m)
#pragma unroll
      for (int n = 0; n < 4; ++n) {
        int cl = wc * 64 + n * 16 + lr;
        float bv = bias ? bias[n0 + cl] : 0.f;
        bf16x4 tmp;
#pragma unroll
        for (int r = 0; r < 4; ++r) tmp[r] = (__bf16)(acc[m][n][r] + bv);
        int rl0 = wr * 64 + m * 16 + lg * 4;
        *(bf16x4*)&Cs[cl * 136 + rl0] = tmp;
      }
    __syncthreads();
    // copy out: C[batch][n0+c][m0%tok + row]
    int c = t >> 1, half = t & 1;
    long batch = m0 / tokPerBatch;
    int tok0 = (m0 % tokPerBatch) + half * 64;
    __bf16* C = (__bf16*)Cv + batch * (long)N * tokPerBatch + (long)(n0 + c) * tokPerBatch + tok0;
#pragma unroll
    for (int j = 0; j < 8; ++j)
      *(bf16x8*)(C + j * 8) = *(const bf16x8*)&Cs[c * 136 + half * 64 + j * 8];
  }
}

// ---------------- QK^T + exp + row-sum kernel ----------------
// grid: (128 q-tiles, 1, 4 batches), block 256 = 4 waves.
// Block owns 16 q-rows; wave w handles key-tiles kt = 4j + w.
__global__ __launch_bounds__(256) void qk_exp_kernel(
    const __bf16* __restrict__ Q, const __bf16* __restrict__ Kmat,
    __bf16* __restrict__ E1, __bf16* __restrict__ E2, float* __restrict__ rl) {
  const int t = threadIdx.x, w = t >> 6, l = t & 63, lr = l & 15, lg = l >> 4;
  const int b = blockIdx.z, qt = blockIdx.x;
  const long qrow0 = (long)b * 2048 + qt * 16;

  const __bf16* Qrow = Q + (qrow0 + lr) * 1024;
  bf16x8 q1[16], q2[16];
#pragma unroll
  for (int c = 0; c < 16; ++c) q1[c] = *(const bf16x8*)&Qrow[c * 32 + lg * 8];
#pragma unroll
  for (int c = 0; c < 16; ++c) q2[c] = *(const bf16x8*)&Qrow[512 + c * 32 + lg * 8];

  float sa1[4] = {0.f, 0.f, 0.f, 0.f}, sa2[4] = {0.f, 0.f, 0.f, 0.f};
  const float s = 0.03125f;  // 1/sqrt(1024)
  __bf16* e1p = E1 + (qrow0 + lg * 4) * 2048 + lr;
  __bf16* e2p = E2 + (qrow0 + lg * 4) * 2048 + lr;

  for (int j = 0; j < 32; ++j) {
    const int kt = j * 4 + w;
    const __bf16* Krow = Kmat + ((long)b * 2048 + kt * 16 + lr) * 1024;
    f32x4 s1 = {0.f, 0.f, 0.f, 0.f}, s2 = {0.f, 0.f, 0.f, 0.f};
#pragma unroll
    for (int c = 0; c < 16; ++c) {
      bf16x8 kf = *(const bf16x8*)&Krow[c * 32 + lg * 8];
      s1 = __builtin_amdgcn_mfma_f32_16x16x32_bf16(q1[c], kf, s1, 0, 0, 0);
    }
#pragma unroll
    for (int c = 0; c < 16; ++c) {
      bf16x8 kf = *(const bf16x8*)&Krow[512 + c * 32 + lg * 8];
      s2 = __builtin_amdgcn_mfma_f32_16x16x32_bf16(q2[c], kf, s2, 0, 0, 0);
    }
#pragma unroll
    for (int r = 0; r < 4; ++r) {
      float e1v = __expf(s1[r] * s), e2v = __expf(s2[r] * s);
      sa1[r] += e1v;
      sa2[r] += e2v;
      e1p[(long)r * 2048 + kt * 16] = (__bf16)e1v;
      e2p[(long)r * 2048 + kt * 16] = (__bf16)e2v;
    }
  }

  // reduce across the 16 column-lanes
#pragma unroll
  for (int r = 0; r < 4; ++r) {
#pragma unroll
    for (int msk = 1; msk < 16; msk <<= 1) {
      sa1[r] += __shfl_xor(sa1[r], msk, 64);
      sa2[r] += __shfl_xor(sa2[r], msk, 64);
    }
  }
  __shared__ float red[4][2][16];
  if (lr == 0) {
#pragma unroll
    for (int r = 0; r < 4; ++r) {
      red[w][0][lg * 4 + r] = sa1[r];
      red[w][1][lg * 4 + r] = sa2[r];
    }
  }
  __syncthreads();
  if (t < 16) {
    float l1 = red[0][0][t] + red[1][0][t] + red[2][0][t] + red[3][0][t];
    float l2 = red[0][1][t] + red[1][1][t] + red[2][1][t] + red[3][1][t];
    rl[(qrow0 + t) * 2] = 1.0f / l1;
    rl[(qrow0 + t) * 2 + 1] = 1.0f / l2;
  }
}

// ---------------- combine: P = E1*rl1 - scalar*E2*rl2 (in-place into E1) ----------------
__global__ __launch_bounds__(256) void combine_kernel(
    __bf16* __restrict__ P, const __bf16* __restrict__ E2,
    const float* __restrict__ rl, const float* __restrict__ scalar) {
  const float sc = scalar[0];
  const long total = (long)4 * 2048 * 2048 / 8;
  const long stride = (long)gridDim.x * blockDim.x;
  for (long g = (long)blockIdx.x * blockDim.x + threadIdx.x; g < total; g += stride) {
    long row = g >> 8;  // 256 groups of 8 per 2048-row
    float rl1 = rl[row * 2], rl2 = rl[row * 2 + 1];
    bf16x8 e1 = *(bf16x8*)(P + g * 8);
    bf16x8 e2 = *(const bf16x8*)(E2 + g * 8);
    bf16x8 o;
#pragma unroll
    for (int i = 0; i < 8; ++i)
      o[i] = (__bf16)((float)e1[i] * rl1 - sc * (float)e2[i] * rl2);
    *(bf16x8*)(P + g * 8) = o;
  }
}

__global__ void diag_kernel(float* out, float v) { out[0] = v; }

// ---------------- host ----------------
extern "C" void kernel_launch(void* const* d_in, const int* in_sizes, int n_in,
                              void* d_out, int out_size, void* d_ws, size_t ws_size,
                              hipStream_t stream) {
  const float* hs = (const float*)d_in[0];
  const float* Wq = (const float*)d_in[1];
  const float* bq = (const float*)d_in[2];
  const float* Wk = (const float*)d_in[3];
  const float* bk = (const float*)d_in[4];
  const float* Wv = (const float*)d_in[5];
  const float* bv = (const float*)d_in[6];
  const float* sc = (const float*)d_in[7];

  const long SZ_QKV = (long)4 * 2048 * 1024;  // 8388608
  const long SZ_E = (long)4 * 2048 * 2048;    // 16777216
  const size_t NEED = (size_t)(SZ_QKV * 2) * 4 + (size_t)(SZ_E * 2) * 2 +
                      (size_t)3 * 1024 * 1024 * 2 + (size_t)4 * 2048 * 2 * 4;
  if (ws_size < NEED) {  // diagnosable failure: absmax ~= ws_size
    diag_kernel<<<dim3(1), dim3(1), 0, stream>>>((float*)d_out, (float)ws_size);
    return;
  }

  char* ws = (char*)d_ws;
  __bf16* Qb = (__bf16*)ws;   ws += SZ_QKV * 2;
  __bf16* Kb = (__bf16*)ws;   ws += SZ_QKV * 2;
  __bf16* VT = (__bf16*)ws;   ws += SZ_QKV * 2;
  __bf16* E1 = (__bf16*)ws;   ws += SZ_E * 2;
  __bf16* E2 = (__bf16*)ws;   ws += SZ_E * 2;
  __bf16* hsb = (__bf16*)ws;  ws += SZ_QKV * 2;
  __bf16* Wqb = (__bf16*)ws;  ws += (long)1024 * 1024 * 2;
  __bf16* Wkb = (__bf16*)ws;  ws += (long)1024 * 1024 * 2;
  __bf16* Wvb = (__bf16*)ws;  ws += (long)1024 * 1024 * 2;
  float* rl = (float*)ws;

  dim3 blk(256);
  cvt_f32_bf16<<<dim3(2048), blk, 0, stream>>>(hs, hsb, SZ_QKV);
  cvt_f32_bf16<<<dim3(512), blk, 0, stream>>>(Wq, Wqb, (long)1024 * 1024);
  cvt_f32_bf16<<<dim3(512), blk, 0, stream>>>(Wk, Wkb, (long)1024 * 1024);
  cvt_f32_bf16<<<dim3(512), blk, 0, stream>>>(Wv, Wvb, (long)1024 * 1024);

  dim3 gProj(8, 64, 1);
  gemm_bt<0><<<gProj, blk, 0, stream>>>(hsb, Wqb, Qb, bq, 8192, 1024, 1024, 0, 0, 0, 2048);
  gemm_bt<0><<<gProj, blk, 0, stream>>>(hsb, Wkb, Kb, bk, 8192, 1024, 1024, 0, 0, 0, 2048);
  gemm_bt<1><<<gProj, blk, 0, stream>>>(hsb, Wvb, VT, bv, 8192, 1024, 1024, 0, 0, 0, 2048);

  qk_exp_kernel<<<dim3(128, 1, 4), blk, 0, stream>>>(Qb, Kb, E1, E2, rl);
  combine_kernel<<<dim3(2048), blk, 0, stream>>>(E1, E2, rl, sc);

  gemm_bt<2><<<dim3(8, 16, 4), blk, 0, stream>>>(E1, VT, d_out, nullptr,
      2048, 1024, 2048, (long)2048 * 2048, (long)1024 * 2048, (long)2048 * 1024, 2048);
}

// Round 5
// 363.208 us; speedup vs baseline: 1.4369x; 1.4369x over previous
//
#include <hip/hip_runtime.h>

typedef __attribute__((ext_vector_type(8))) __bf16 bf16x8;
typedef __attribute__((ext_vector_type(4))) __bf16 bf16x4;
typedef __attribute__((ext_vector_type(4))) float f32x4;

#define GLD16(gp, lp) __builtin_amdgcn_global_load_lds( \
    (const __attribute__((address_space(1))) void*)(gp), \
    (__attribute__((address_space(3))) void*)(lp), 16, 0, 0)

// ---------------- f32 -> bf16 conversion ----------------
__global__ __launch_bounds__(256) void cvt_f32_bf16(const float* __restrict__ in,
                                                    __bf16* __restrict__ out, long n) {
  long stride = (long)gridDim.x * 256 * 8;
  for (long i = ((long)blockIdx.x * 256 + threadIdx.x) * 8; i < n; i += stride) {
    float4 a = *(const float4*)(in + i);
    float4 b = *(const float4*)(in + i + 4);
    bf16x8 o;
    o[0] = (__bf16)a.x; o[1] = (__bf16)a.y; o[2] = (__bf16)a.z; o[3] = (__bf16)a.w;
    o[4] = (__bf16)b.x; o[5] = (__bf16)b.y; o[6] = (__bf16)b.z; o[7] = (__bf16)b.w;
    *(bf16x8*)(out + i) = o;
  }
}

__global__ __launch_bounds__(256) void zero_f32(float* __restrict__ p, int n) {
  int i = blockIdx.x * 256 + threadIdx.x;
  if (i < n) p[i] = 0.f;
}

// ---------------- generic C = A @ B^T (+bias) GEMM ----------------
// A [M][K], BT [N][K] bf16 row-major (both K-major). BM=BN=128, BK=32, 4 waves.
// EPI 0: C bf16 row-major [M][N] + bias
// EPI 1: C bf16 transposed per batch: C[batch][n][tok], batch=row/tokPerBatch (+bias)
// EPI 2: C f32 row-major [M][N], no bias
template <int EPI>
__global__ __launch_bounds__(256) void gemm_bt(
    const __bf16* __restrict__ A, const __bf16* __restrict__ BT,
    void* __restrict__ Cv, const float* __restrict__ bias,
    int M, int N, int K,
    long aBatch, long bBatch, long cBatch, int tokPerBatch) {
  __shared__ __bf16 As[128 * 32];
  __shared__ __bf16 Bs[128 * 32];

  const int t = threadIdx.x;
  const int w = t >> 6, l = t & 63;
  const int wr = w >> 1, wc = w & 1;
  const int lr = l & 15, lg = l >> 4;

  const int m0 = blockIdx.y * 128, n0 = blockIdx.x * 128;
  const int z = blockIdx.z;
  const __bf16* Ab = A + (long)z * aBatch + (long)m0 * K;
  const __bf16* Bb = BT + (long)z * bBatch + (long)n0 * K;

  // staging map: thread t loads row (t>>2), cols (t&3)*8 .. +7
  const int srow = t >> 2, scol = (t & 3) * 8;
  const __bf16* ag0 = Ab + (long)srow * K + scol;
  const __bf16* bg0 = Bb + (long)srow * K + scol;
  char* lA = (char*)As + w * 1024;  // wave-uniform LDS base; HW adds lane*16
  char* lB = (char*)Bs + w * 1024;

  f32x4 acc[4][4];
#pragma unroll
  for (int m = 0; m < 4; ++m)
#pragma unroll
    for (int n = 0; n < 4; ++n) acc[m][n] = (f32x4){0.f, 0.f, 0.f, 0.f};

  for (int k0 = 0; k0 < K; k0 += 32) {
    __syncthreads();
    GLD16(ag0 + k0, lA);
    GLD16(ag0 + (long)64 * K + k0, lA + 4096);
    GLD16(bg0 + k0, lB);
    GLD16(bg0 + (long)64 * K + k0, lB + 4096);
    __syncthreads();

    bf16x8 af[4], bf[4];
#pragma unroll
    for (int m = 0; m < 4; ++m)
      af[m] = *(const bf16x8*)&As[(wr * 64 + m * 16 + lr) * 32 + lg * 8];
#pragma unroll
    for (int n = 0; n < 4; ++n)
      bf[n] = *(const bf16x8*)&Bs[(wc * 64 + n * 16 + lr) * 32 + lg * 8];
#pragma unroll
    for (int m = 0; m < 4; ++m)
#pragma unroll
      for (int n = 0; n < 4; ++n)
        acc[m][n] = __builtin_amdgcn_mfma_f32_16x16x32_bf16(af[m], bf[n], acc[m][n], 0, 0, 0);
  }

  if constexpr (EPI == 0) {
    __bf16* C = (__bf16*)Cv + (long)z * cBatch;
#pragma unroll
    for (int m = 0; m < 4; ++m)
#pragma unroll
      for (int n = 0; n < 4; ++n) {
        int colg = n0 + wc * 64 + n * 16 + lr;
        float bv = bias ? bias[colg] : 0.f;
#pragma unroll
        for (int r = 0; r < 4; ++r) {
          int rowg = m0 + wr * 64 + m * 16 + lg * 4 + r;
          C[(long)rowg * N + colg] = (__bf16)(acc[m][n][r] + bv);
        }
      }
  } else if constexpr (EPI == 2) {
    float* C = (float*)Cv + (long)z * cBatch;
#pragma unroll
    for (int m = 0; m < 4; ++m)
#pragma unroll
      for (int n = 0; n < 4; ++n) {
        int colg = n0 + wc * 64 + n * 16 + lr;
#pragma unroll
        for (int r = 0; r < 4; ++r) {
          int rowg = m0 + wr * 64 + m * 16 + lg * 4 + r;
          C[(long)rowg * N + colg] = acc[m][n][r];
        }
      }
  } else {
    // transposed epilogue via LDS: Cs[col][row], ld = 136
    __shared__ __bf16 Cs[128 * 136];
#pragma unroll
    for (int m = 0; m < 4; ++m)
#pragma unroll
      for (int n = 0; n < 4; ++n) {
        int cl = wc * 64 + n * 16 + lr;
        float bv = bias ? bias[n0 + cl] : 0.f;
        bf16x4 tmp;
#pragma unroll
        for (int r = 0; r < 4; ++r) tmp[r] = (__bf16)(acc[m][n][r] + bv);
        int rl0 = wr * 64 + m * 16 + lg * 4;
        *(bf16x4*)&Cs[cl * 136 + rl0] = tmp;
      }
    __syncthreads();
    // copy out: C[batch][n0+c][m0%tok + row]
    int c = t >> 1, half = t & 1;
    long batch = m0 / tokPerBatch;
    int tok0 = (m0 % tokPerBatch) + half * 64;
    __bf16* C = (__bf16*)Cv + batch * (long)N * tokPerBatch + (long)(n0 + c) * tokPerBatch + tok0;
#pragma unroll
    for (int j = 0; j < 8; ++j)
      *(bf16x8*)(C + j * 8) = *(const bf16x8*)&Cs[c * 136 + half * 64 + j * 8];
  }
}

// ---------------- QK^T + exp + row-sum GEMM ----------------
// grid (16 n-tiles, 16 m-tiles, 8 = batch*2+half), 256 threads.
// E = exp(s * Q_half K_half^T) for this (batch,half); row sums atomically
// accumulated into sums[half*8192 + batch*2048 + row].
__global__ __launch_bounds__(256) void qk_gemm(
    const __bf16* __restrict__ Q, const __bf16* __restrict__ Kmat,
    __bf16* __restrict__ E1, __bf16* __restrict__ E2,
    float* __restrict__ sums) {
  __shared__ __bf16 As[128 * 32];
  __shared__ __bf16 Bs[128 * 32];
  __shared__ __bf16 Cs[128 * 136];  // [row][col] tile of E, ld=136

  const int t = threadIdx.x;
  const int w = t >> 6, l = t & 63;
  const int wr = w >> 1, wc = w & 1;
  const int lr = l & 15, lg = l >> 4;
  const int z = blockIdx.z, b = z >> 1, h = z & 1;
  const int m0 = blockIdx.y * 128, n0 = blockIdx.x * 128;

  const __bf16* Ab = Q + (long)b * 2048 * 1024 + (long)m0 * 1024 + h * 512;
  const __bf16* Bb = Kmat + (long)b * 2048 * 1024 + (long)n0 * 1024 + h * 512;

  const int srow = t >> 2, scol = (t & 3) * 8;
  const __bf16* ag0 = Ab + (long)srow * 1024 + scol;
  const __bf16* bg0 = Bb + (long)srow * 1024 + scol;
  char* lA = (char*)As + w * 1024;
  char* lB = (char*)Bs + w * 1024;

  f32x4 acc[4][4];
#pragma unroll
  for (int m = 0; m < 4; ++m)
#pragma unroll
    for (int n = 0; n < 4; ++n) acc[m][n] = (f32x4){0.f, 0.f, 0.f, 0.f};

  for (int k0 = 0; k0 < 512; k0 += 32) {
    __syncthreads();
    GLD16(ag0 + k0, lA);
    GLD16(ag0 + (long)64 * 1024 + k0, lA + 4096);
    GLD16(bg0 + k0, lB);
    GLD16(bg0 + (long)64 * 1024 + k0, lB + 4096);
    __syncthreads();

    bf16x8 af[4], bf[4];
#pragma unroll
    for (int m = 0; m < 4; ++m)
      af[m] = *(const bf16x8*)&As[(wr * 64 + m * 16 + lr) * 32 + lg * 8];
#pragma unroll
    for (int n = 0; n < 4; ++n)
      bf[n] = *(const bf16x8*)&Bs[(wc * 64 + n * 16 + lr) * 32 + lg * 8];
#pragma unroll
    for (int m = 0; m < 4; ++m)
#pragma unroll
      for (int n = 0; n < 4; ++n)
        acc[m][n] = __builtin_amdgcn_mfma_f32_16x16x32_bf16(af[m], bf[n], acc[m][n], 0, 0, 0);
  }

  // epilogue: exp, stage to LDS, partial row sums
  const float s = 0.03125f;  // 1/sqrt(1024)
  float ps[4][4];
#pragma unroll
  for (int m = 0; m < 4; ++m)
#pragma unroll
    for (int r = 0; r < 4; ++r) ps[m][r] = 0.f;

#pragma unroll
  for (int m = 0; m < 4; ++m)
#pragma unroll
    for (int n = 0; n < 4; ++n) {
      int cl = wc * 64 + n * 16 + lr;
      int rl0 = wr * 64 + m * 16 + lg * 4;
#pragma unroll
      for (int r = 0; r < 4; ++r) {
        float e = __expf(acc[m][n][r] * s);
        ps[m][r] += e;
        Cs[(rl0 + r) * 136 + cl] = (__bf16)e;
      }
    }

  // reduce ps across the 16 lr-lanes (masks < 16 stay within the group)
#pragma unroll
  for (int m = 0; m < 4; ++m)
#pragma unroll
    for (int r = 0; r < 4; ++r) {
#pragma unroll
      for (int msk = 1; msk < 16; msk <<= 1)
        ps[m][r] += __shfl_xor(ps[m][r], msk, 64);
    }
  if (lr == 0) {
    float* sb = sums + (long)h * 8192 + (long)b * 2048 + m0 + wr * 64;
#pragma unroll
    for (int m = 0; m < 4; ++m)
#pragma unroll
      for (int r = 0; r < 4; ++r)
        atomicAdd(&sb[m * 16 + lg * 4 + r], ps[m][r]);
  }

  __syncthreads();
  // coalesced E write: thread t -> row t>>1, col half (t&1)*64, 8 x b128
  __bf16* EX = h ? E2 : E1;
  int row = t >> 1, half = t & 1;
  __bf16* C = EX + ((long)b * 2048 + m0 + row) * 2048 + n0 + half * 64;
  const __bf16* src = &Cs[row * 136 + half * 64];
#pragma unroll
  for (int j = 0; j < 8; ++j)
    *(bf16x8*)(C + j * 8) = *(const bf16x8*)(src + j * 8);
}

// ---------------- combine: P = E1/l1 - scalar*E2/l2 (in-place into E1) ----------------
__global__ __launch_bounds__(256) void combine_kernel(
    __bf16* __restrict__ P, const __bf16* __restrict__ E2,
    const float* __restrict__ sums, const float* __restrict__ scalar) {
  const float sc = scalar[0];
  const long total = (long)4 * 2048 * 2048 / 8;
  const long stride = (long)gridDim.x * blockDim.x;
  for (long g = (long)blockIdx.x * blockDim.x + threadIdx.x; g < total; g += stride) {
    long row = g >> 8;  // 256 groups of 8 per 2048-col row; row in [0,8192)
    float rl1 = 1.0f / sums[row];
    float rl2 = sc / sums[8192 + row];
    bf16x8 e1 = *(bf16x8*)(P + g * 8);
    bf16x8 e2 = *(const bf16x8*)(E2 + g * 8);
    bf16x8 o;
#pragma unroll
    for (int i = 0; i < 8; ++i)
      o[i] = (__bf16)((float)e1[i] * rl1 - (float)e2[i] * rl2);
    *(bf16x8*)(P + g * 8) = o;
  }
}

__global__ void diag_kernel(float* out, float v) { out[0] = v; }

// ---------------- host ----------------
extern "C" void kernel_launch(void* const* d_in, const int* in_sizes, int n_in,
                              void* d_out, int out_size, void* d_ws, size_t ws_size,
                              hipStream_t stream) {
  const float* hs = (const float*)d_in[0];
  const float* Wq = (const float*)d_in[1];
  const float* bq = (const float*)d_in[2];
  const float* Wk = (const float*)d_in[3];
  const float* bk = (const float*)d_in[4];
  const float* Wv = (const float*)d_in[5];
  const float* bv = (const float*)d_in[6];
  const float* sc = (const float*)d_in[7];

  const long SZ_QKV = (long)4 * 2048 * 1024;  // 8388608
  const long SZ_E = (long)4 * 2048 * 2048;    // 16777216
  const size_t NEED = (size_t)(SZ_QKV * 2) * 4 + (size_t)(SZ_E * 2) * 2 +
                      (size_t)3 * 1024 * 1024 * 2 + (size_t)4 * 2048 * 2 * 4;
  if (ws_size < NEED) {  // diagnosable failure: absmax ~= ws_size
    diag_kernel<<<dim3(1), dim3(1), 0, stream>>>((float*)d_out, (float)ws_size);
    return;
  }

  char* ws = (char*)d_ws;
  __bf16* Qb = (__bf16*)ws;   ws += SZ_QKV * 2;
  __bf16* Kb = (__bf16*)ws;   ws += SZ_QKV * 2;
  __bf16* VT = (__bf16*)ws;   ws += SZ_QKV * 2;
  __bf16* E1 = (__bf16*)ws;   ws += SZ_E * 2;
  __bf16* E2 = (__bf16*)ws;   ws += SZ_E * 2;
  __bf16* hsb = (__bf16*)ws;  ws += SZ_QKV * 2;
  __bf16* Wqb = (__bf16*)ws;  ws += (long)1024 * 1024 * 2;
  __bf16* Wkb = (__bf16*)ws;  ws += (long)1024 * 1024 * 2;
  __bf16* Wvb = (__bf16*)ws;  ws += (long)1024 * 1024 * 2;
  float* sums = (float*)ws;   // [2][8192]

  dim3 blk(256);
  cvt_f32_bf16<<<dim3(2048), blk, 0, stream>>>(hs, hsb, SZ_QKV);
  cvt_f32_bf16<<<dim3(512), blk, 0, stream>>>(Wq, Wqb, (long)1024 * 1024);
  cvt_f32_bf16<<<dim3(512), blk, 0, stream>>>(Wk, Wkb, (long)1024 * 1024);
  cvt_f32_bf16<<<dim3(512), blk, 0, stream>>>(Wv, Wvb, (long)1024 * 1024);
  zero_f32<<<dim3(64), blk, 0, stream>>>(sums, 16384);

  dim3 gProj(8, 64, 1);
  gemm_bt<0><<<gProj, blk, 0, stream>>>(hsb, Wqb, Qb, bq, 8192, 1024, 1024, 0, 0, 0, 2048);
  gemm_bt<0><<<gProj, blk, 0, stream>>>(hsb, Wkb, Kb, bk, 8192, 1024, 1024, 0, 0, 0, 2048);
  gemm_bt<1><<<gProj, blk, 0, stream>>>(hsb, Wvb, VT, bv, 8192, 1024, 1024, 0, 0, 0, 2048);

  qk_gemm<<<dim3(16, 16, 8), blk, 0, stream>>>(Qb, Kb, E1, E2, sums);
  combine_kernel<<<dim3(2048), blk, 0, stream>>>(E1, E2, sums, sc);

  gemm_bt<2><<<dim3(8, 16, 4), blk, 0, stream>>>(E1, VT, d_out, nullptr,
      2048, 1024, 2048, (long)2048 * 2048, (long)1024 * 2048, (long)2048 * 1024, 2048);
}